// Round 12
// baseline (309.438 us; speedup 1.0000x reference)
//
#include <hip/hip_runtime.h>
#include <hip/hip_fp16.h>
#include <math.h>

// Problem constants (match reference)
#define R_TOT 4096
#define L_LEN 128
#define D_DIM 200
#define A_DIM 20
#define NEGK  2
#define B_SZ  1024
#define NNZ_C 20480
#define RN_TOT (R_TOT*NEGK)
#define S_TOT (R_TOT + RN_TOT)
#define VOCAB_C 32000
#define VHALF 16000
#define EPS_ 1e-12f
#define SLOT_CAP 64          // Poisson(20) max bin ~45; 64 is safe
#define NBUCK_BLK 160        // 160*256 = 40960 = 2*NNZ_C

__device__ __forceinline__ float4 unpack4(const uint2 u) {
  union { unsigned v; __half2 h; } c0, c1;
  c0.v = u.x; c1.v = u.y;
  const float2 f0 = __half22float2(c0.h);
  const float2 f1 = __half22float2(c1.h);
  return make_float4(f0.x, f0.y, f1.x, f1.y);
}

// ---- packed fp16 dot: v_dot2_f32_f16 (exact f32 products, f32 accumulate) ----
typedef _Float16 h2v __attribute__((ext_vector_type(2)));
__device__ __forceinline__ float fdot2u(unsigned a, unsigned b, float c) {
  union { unsigned u; h2v h; } ua, ub;
  ua.u = a; ub.u = b;
  return __builtin_amdgcn_fdot2(ua.h, ub.h, c, false);
}
__device__ __forceinline__ float dot8f(const uint4 q, const uint4 w, float c) {
  float s = c;
  s = fdot2u(q.x, w.x, s); s = fdot2u(q.y, w.y, s);
  s = fdot2u(q.z, w.z, s); s = fdot2u(q.w, w.w, s);
  return s;
}

// ---- DPP wave reductions (VALU pipe, zero DS-pipe traffic) ----
#define DPPI(old_, src_, ctrl, rmask) \
  __builtin_amdgcn_update_dpp(old_, src_, ctrl, rmask, 0xf, false)

__device__ __forceinline__ float dpp_sum32(float s) {   // lanes 31 & 63 hold half-wave sums
  s += __int_as_float(DPPI(0, __float_as_int(s), 0x111, 0xf));   // row_shr:1
  s += __int_as_float(DPPI(0, __float_as_int(s), 0x112, 0xf));   // row_shr:2
  s += __int_as_float(DPPI(0, __float_as_int(s), 0x114, 0xf));   // row_shr:4
  s += __int_as_float(DPPI(0, __float_as_int(s), 0x118, 0xf));   // row_shr:8
  s += __int_as_float(DPPI(0, __float_as_int(s), 0x142, 0xa));   // row_bcast15
  return s;
}
__device__ __forceinline__ float dpp_sum64(float s) {   // lane 63 holds wave sum
  s = dpp_sum32(s);
  s += __int_as_float(DPPI(0, __float_as_int(s), 0x143, 0xc));   // row_bcast31
  return s;
}
__device__ __forceinline__ float dpp_max64(float s) {   // lane 63 holds wave max
  s = fmaxf(s, __int_as_float(DPPI(__float_as_int(s), __float_as_int(s), 0x111, 0xf)));
  s = fmaxf(s, __int_as_float(DPPI(__float_as_int(s), __float_as_int(s), 0x112, 0xf)));
  s = fmaxf(s, __int_as_float(DPPI(__float_as_int(s), __float_as_int(s), 0x114, 0xf)));
  s = fmaxf(s, __int_as_float(DPPI(__float_as_int(s), __float_as_int(s), 0x118, 0xf)));
  s = fmaxf(s, __int_as_float(DPPI(__float_as_int(s), __float_as_int(s), 0x142, 0xa)));
  s = fmaxf(s, __int_as_float(DPPI(__float_as_int(s), __float_as_int(s), 0x143, 0xc)));
  return s;
}

// ---------------- K0: cast emb -> fp16 table; block 0 also zeroes bucket counters ----------------
__global__ __launch_bounds__(256) void k_cast(
    const float* __restrict__ emb, ushort* __restrict__ emb_h, int* __restrict__ cnt)
{
  if (blockIdx.x == 0) {
    for (int i = threadIdx.x; i < 2*B_SZ; i += 256) cnt[i] = 0;
  }
  const int idx = blockIdx.x*256 + threadIdx.x;
  if (idx < (VOCAB_C*D_DIM)/4) {
    const float4 v = reinterpret_cast<const float4*>(emb)[idx];
    ushort4 o;
    o.x = __half_as_ushort(__float2half(v.x));
    o.y = __half_as_ushort(__float2half(v.y));
    o.z = __half_as_ushort(__float2half(v.z));
    o.w = __half_as_ushort(__float2half(v.w));
    reinterpret_cast<ushort4*>(emb_h)[idx] = o;
  }
}

// ---------------- K1: means, vocab-range phased + COMPACTED row list + bucket tail ----------------
// R8-verified phase split (6.4 MB working set -> L2-resident). R12: instead of
// full-length masked loops (half dummy loads + full VALU), a 2-wave ballot/popcount
// builds the stable-ordered compacted list of in-range rows (avg 64/128); threads
// gather only compacted rows: batch 1 always, batch 2 skipped when j+64 >= n_in.
// FMA-with-0 masking on tails -> identical values up to j-partition reorder (~1e-6).
#define ACC8M(Q, M) { \
  const float4 e0_ = unpack4(make_uint2((Q).x,(Q).y)); \
  const float4 e1_ = unpack4(make_uint2((Q).z,(Q).w)); \
  sA.x = fmaf(M, e0_.x, sA.x); sA.y = fmaf(M, e0_.y, sA.y); \
  sA.z = fmaf(M, e0_.z, sA.z); sA.w = fmaf(M, e0_.w, sA.w); \
  sB.x = fmaf(M, e1_.x, sB.x); sB.y = fmaf(M, e1_.y, sB.y); \
  sB.z = fmaf(M, e1_.z, sB.z); sB.w = fmaf(M, e1_.w, sB.w); }

__global__ __launch_bounds__(256, 8) void k_means_phase(
    const int* __restrict__ hist, const int* __restrict__ neg,
    const ushort* __restrict__ emb_h,
    float* __restrict__ ys_all, float* __restrict__ zn_all,
    const int* __restrict__ uidx, const float* __restrict__ uval,
    const int* __restrict__ iidx, const float* __restrict__ ival,
    int* __restrict__ cnt, int* __restrict__ scol, float* __restrict__ sval,
    int lo, int finalize)
{
  const int sb = blockIdx.x;
  const int tid = threadIdx.x;

  if (sb >= S_TOT) {            // bucket tail — phase A only (phase B grid = S_TOT)
    const int g = (sb - S_TOT)*256 + tid;
    if (g < NNZ_C) {
      const int b = uidx[g];
      const int slot = atomicAdd(&cnt[b], 1);
      if (slot < SLOT_CAP) {
        scol[b*SLOT_CAP + slot] = uidx[NNZ_C + g];
        sval[b*SLOT_CAP + slot] = uval[g];
      }
    } else {
      const int g2 = g - NNZ_C;
      const int b = iidx[g2];
      const int slot = atomicAdd(&cnt[B_SZ + b], 1);
      if (slot < SLOT_CAP) {
        scol[(B_SZ + b)*SLOT_CAP + slot] = iidx[NNZ_C + g2];
        sval[(B_SZ + b)*SLOT_CAP + slot] = ival[g2];
      }
    }
    return;
  }

  __shared__ int widx[L_LEN];
  __shared__ int rows_in[L_LEN];
  __shared__ int cnt01[2];
  __shared__ __align__(16) float part[8][D_DIM];
  const bool is_pos = (sb < R_TOT);
  const int* src = is_pos ? (hist + (size_t)sb*L_LEN)
                          : (neg + (size_t)(sb - R_TOT)*L_LEN);
  if (tid < L_LEN) widx[tid] = src[tid];
  __syncthreads();

  // ---- compact in-range rows (stable order; waves 0,1 handle 64 rows each) ----
  bool inr = false; int wrow = 0; int pos = 0;
  if (tid < 128) {
    wrow = widx[tid];
    inr = ((unsigned)(wrow - lo) < (unsigned)VHALF);
    const unsigned long long mb = __ballot(inr);
    pos = (int)__popcll(mb & ((1ull << (tid & 63)) - 1));
    if ((tid & 63) == 0) cnt01[tid >> 6] = (int)__popcll(mb);
  }
  __syncthreads();
  const int n_in = cnt01[0] + cnt01[1];
  if (tid < 128 && inr) rows_in[((tid >= 64) ? cnt01[0] : 0) + pos] = wrow;
  __syncthreads();

  const int c5 = tid & 31;       // column chunk (active if < 25)
  const int j  = tid >> 5;       // 0..7 row group
  float4 sA = {0.f,0.f,0.f,0.f}, sB = {0.f,0.f,0.f,0.f};
  if (c5 < 25) {
    const size_t coff = 8*c5;
    {                            // batch 1: compacted rows j+8k, k=0..7
      int wv_[8]; float m_[8];
      #pragma unroll
      for (int k = 0; k < 8; ++k) {
        const int ridx = j + 8*k;
        const bool v = ridx < n_in;
        wv_[k] = v ? rows_in[ridx] : 0;
        m_[k]  = v ? 1.f : 0.f;
      }
      const uint4 q0 = *reinterpret_cast<const uint4*>(emb_h + (size_t)wv_[0]*D_DIM + coff);
      const uint4 q1 = *reinterpret_cast<const uint4*>(emb_h + (size_t)wv_[1]*D_DIM + coff);
      const uint4 q2 = *reinterpret_cast<const uint4*>(emb_h + (size_t)wv_[2]*D_DIM + coff);
      const uint4 q3 = *reinterpret_cast<const uint4*>(emb_h + (size_t)wv_[3]*D_DIM + coff);
      const uint4 q4 = *reinterpret_cast<const uint4*>(emb_h + (size_t)wv_[4]*D_DIM + coff);
      const uint4 q5 = *reinterpret_cast<const uint4*>(emb_h + (size_t)wv_[5]*D_DIM + coff);
      const uint4 q6 = *reinterpret_cast<const uint4*>(emb_h + (size_t)wv_[6]*D_DIM + coff);
      const uint4 q7 = *reinterpret_cast<const uint4*>(emb_h + (size_t)wv_[7]*D_DIM + coff);
      ACC8M(q0, m_[0]) ACC8M(q1, m_[1]) ACC8M(q2, m_[2]) ACC8M(q3, m_[3])
      ACC8M(q4, m_[4]) ACC8M(q5, m_[5]) ACC8M(q6, m_[6]) ACC8M(q7, m_[7])
    }
    if (j + 64 < n_in) {         // batch 2 only when needed (half-wave uniform)
      int wv_[8]; float m_[8];
      #pragma unroll
      for (int k = 0; k < 8; ++k) {
        const int ridx = j + 64 + 8*k;
        const bool v = ridx < n_in;
        wv_[k] = v ? rows_in[ridx] : 0;
        m_[k]  = v ? 1.f : 0.f;
      }
      const uint4 q0 = *reinterpret_cast<const uint4*>(emb_h + (size_t)wv_[0]*D_DIM + coff);
      const uint4 q1 = *reinterpret_cast<const uint4*>(emb_h + (size_t)wv_[1]*D_DIM + coff);
      const uint4 q2 = *reinterpret_cast<const uint4*>(emb_h + (size_t)wv_[2]*D_DIM + coff);
      const uint4 q3 = *reinterpret_cast<const uint4*>(emb_h + (size_t)wv_[3]*D_DIM + coff);
      const uint4 q4 = *reinterpret_cast<const uint4*>(emb_h + (size_t)wv_[4]*D_DIM + coff);
      const uint4 q5 = *reinterpret_cast<const uint4*>(emb_h + (size_t)wv_[5]*D_DIM + coff);
      const uint4 q6 = *reinterpret_cast<const uint4*>(emb_h + (size_t)wv_[6]*D_DIM + coff);
      const uint4 q7 = *reinterpret_cast<const uint4*>(emb_h + (size_t)wv_[7]*D_DIM + coff);
      ACC8M(q0, m_[0]) ACC8M(q1, m_[1]) ACC8M(q2, m_[2]) ACC8M(q3, m_[3])
      ACC8M(q4, m_[4]) ACC8M(q5, m_[5]) ACC8M(q6, m_[6]) ACC8M(q7, m_[7])
    }
    *reinterpret_cast<float4*>(&part[j][8*c5])     = sA;
    *reinterpret_cast<float4*>(&part[j][8*c5 + 4]) = sB;
  }
  __syncthreads();
  float* dst = is_pos ? (ys_all + (size_t)sb*D_DIM)
                      : (zn_all + (size_t)(sb - R_TOT)*D_DIM);
  if (tid < D_DIM) {
    float a = 0.f;
    #pragma unroll
    for (int j2 = 0; j2 < 8; ++j2) a += part[j2][tid];
    if (finalize) dst[tid] = (dst[tid] + a) * (1.0f/128.0f);
    else          dst[tid] = a;
  }
}

// ---------------- K2: V = Y @ Wm (16 reviews/block) — fp16 output for fdot2 ----------------
#define KB_RT 16
__global__ __launch_bounds__(256, 2) void k_matvec(
    const float* __restrict__ ys_all, const float* __restrict__ Wm,
    ushort* __restrict__ vvh)
{
  __shared__ float ysl[KB_RT][D_DIM];
  const int r0 = blockIdx.x * KB_RT;
  const int tid = threadIdx.x;
  for (int i = tid; i < KB_RT*D_DIM; i += 256)
    ysl[i / D_DIM][i % D_DIM] = ys_all[(size_t)r0*D_DIM + i];
  __syncthreads();
  if (tid < D_DIM) {
    float acc[KB_RT];
    #pragma unroll
    for (int r = 0; r < KB_RT; ++r) acc[r] = 0.f;
    #pragma unroll 4
    for (int k = 0; k < D_DIM; ++k) {
      const float w = Wm[k*D_DIM + tid];
      #pragma unroll
      for (int r = 0; r < KB_RT; ++r) acc[r] += ysl[r][k] * w;
    }
    #pragma unroll
    for (int r = 0; r < KB_RT; ++r)
      vvh[(size_t)(r0 + r)*D_DIM + tid] = __half_as_ushort(__float2half(acc[r]));
  }
}

// ---------------- K3: attn — register tile + DPP + fdot2 (R10-verified, unchanged) ----------------
__global__ __launch_bounds__(512, 8) void k_attn(
    const int* __restrict__ hist, const ushort* __restrict__ emb_h,
    const ushort* __restrict__ vvh,
    const float* __restrict__ Ww, const float* __restrict__ bw,
    const float* __restrict__ Wt, const float* __restrict__ zn_all,
    float* __restrict__ rs_out, float* __restrict__ abae)
{
  __shared__ __align__(16) float part[D_DIM][17];    // padded: conflict-free zs-sum
  __shared__ __align__(16) float ax[L_LEN];
  __shared__ __align__(16) ushort axh[L_LEN];
  __shared__ __align__(16) float zs[D_DIM];
  __shared__ __align__(16) float ubuf[240];
  int*   widx  = reinterpret_cast<int*>(ubuf);
  float* ptile = ubuf;
  float* red   = ubuf + 160;

  const int r = blockIdx.x;
  const int tid = threadIdx.x, lane = tid & 63, wv = tid >> 6;
  const int c5 = tid & 31;
  const int j  = tid >> 5;
  const bool act = (c5 < 25);
  const int coff = 8*c5;

  if (tid < L_LEN) widx[tid] = hist[r*L_LEN + tid];
  uint4 v8u = make_uint4(0,0,0,0);
  if (act) v8u = *reinterpret_cast<const uint4*>(vvh + (size_t)r*D_DIM + coff);
  __syncthreads();                                   // B1

  uint4 q0,q1,q2,q3,q4,q5,q6,q7;
  q0=q1=q2=q3=q4=q5=q6=q7=make_uint4(0,0,0,0);
  float zn0 = 0.f, zn1 = 0.f;
  float p0=0.f,p1=0.f,p2=0.f,p3=0.f,p4=0.f,p5=0.f,p6=0.f,p7=0.f;
  if (act) {
    q0 = *reinterpret_cast<const uint4*>(emb_h + (size_t)widx[j +   0]*D_DIM + coff);
    q1 = *reinterpret_cast<const uint4*>(emb_h + (size_t)widx[j +  16]*D_DIM + coff);
    q2 = *reinterpret_cast<const uint4*>(emb_h + (size_t)widx[j +  32]*D_DIM + coff);
    q3 = *reinterpret_cast<const uint4*>(emb_h + (size_t)widx[j +  48]*D_DIM + coff);
    q4 = *reinterpret_cast<const uint4*>(emb_h + (size_t)widx[j +  64]*D_DIM + coff);
    q5 = *reinterpret_cast<const uint4*>(emb_h + (size_t)widx[j +  80]*D_DIM + coff);
    q6 = *reinterpret_cast<const uint4*>(emb_h + (size_t)widx[j +  96]*D_DIM + coff);
    q7 = *reinterpret_cast<const uint4*>(emb_h + (size_t)widx[j + 112]*D_DIM + coff);
  }
  if (tid < D_DIM) {
    zn0 = zn_all[(size_t)(2*r)*D_DIM + tid];
    zn1 = zn_all[(size_t)(2*r + 1)*D_DIM + tid];
  }
  if (act) {
    p0 = dot8f(q0, v8u, 0.f); p1 = dot8f(q1, v8u, 0.f);
    p2 = dot8f(q2, v8u, 0.f); p3 = dot8f(q3, v8u, 0.f);
    p4 = dot8f(q4, v8u, 0.f); p5 = dot8f(q5, v8u, 0.f);
    p6 = dot8f(q6, v8u, 0.f); p7 = dot8f(q7, v8u, 0.f);
  }
  p0 = dpp_sum32(p0); p1 = dpp_sum32(p1); p2 = dpp_sum32(p2); p3 = dpp_sum32(p3);
  p4 = dpp_sum32(p4); p5 = dpp_sum32(p5); p6 = dpp_sum32(p6); p7 = dpp_sum32(p7);
  if (c5 == 31) {
    ax[j]      = p0; ax[j + 16]  = p1; ax[j + 32]  = p2; ax[j + 48]  = p3;
    ax[j + 64] = p4; ax[j + 80]  = p5; ax[j + 96]  = p6; ax[j + 112] = p7;
  }
  __syncthreads();                                   // B2

  float mx = fmaxf(ax[lane], ax[lane + 64]);
  mx = dpp_max64(mx);
  const float M = __int_as_float(__builtin_amdgcn_readlane(__float_as_int(mx), 63));

  if (tid < L_LEN) {
    const float e = expf(ax[tid] - M);
    axh[tid] = __half_as_ushort(__float2half(e));
    const float s = dpp_sum64(e);
    if (lane == 63) red[1 + wv] = s;
  }
  __syncthreads();                                   // B3'

  if (act) {
    const int Y  = 25*j + c5;
    const int l0 = (8*Y) & 127;
    const int v0 = Y >> 4;
    const int sl = Y & 15;
    const uint4 ax8u = *reinterpret_cast<const uint4*>(axh + l0);
    part[v0 +   0][sl] = dot8f(q0, ax8u, 0.f);
    part[v0 +  25][sl] = dot8f(q1, ax8u, 0.f);
    part[v0 +  50][sl] = dot8f(q2, ax8u, 0.f);
    part[v0 +  75][sl] = dot8f(q3, ax8u, 0.f);
    part[v0 + 100][sl] = dot8f(q4, ax8u, 0.f);
    part[v0 + 125][sl] = dot8f(q5, ax8u, 0.f);
    part[v0 + 150][sl] = dot8f(q6, ax8u, 0.f);
    part[v0 + 175][sl] = dot8f(q7, ax8u, 0.f);
  }
  __syncthreads();                                   // B4'

  if (tid < D_DIM) {
    const float Sinv = 1.0f / (red[1] + red[2]);
    float s = 0.f;
    #pragma unroll
    for (int i = 0; i < 16; ++i) s += part[tid][i];
    zs[tid] = s * Sinv;
  }
  __syncthreads();                                   // B5'

  if (tid < 160) {
    const int a = tid % 20, jj = tid / 20;
    float s = 0.f;
    #pragma unroll
    for (int ii = 0; ii < 25; ++ii) {
      const int d = jj + 8*ii;
      s += zs[d] * Ww[a*D_DIM + d];
    }
    ptile[tid] = s;
  }
  __syncthreads();                                   // B6'
  if (tid < A_DIM) {
    float s = bw[tid];
    #pragma unroll
    for (int jj = 0; jj < 8; ++jj) s += ptile[jj*20 + tid];
    red[2 + tid] = s;
  }
  __syncthreads();                                   // B7'

  float rsd = 0.f, zsd = 0.f;
  if (tid < D_DIM) {
    float acc = 0.f;
    #pragma unroll
    for (int a = 0; a < A_DIM; ++a) acc += red[2+a] * Wt[tid*A_DIM + a];
    rsd = acc; zsd = zs[tid];
    rs_out[(size_t)r*D_DIM + tid] = acc;
  } else { zn0 = 0.f; zn1 = 0.f; }
  float a0 = dpp_sum64(rsd*rsd), a1 = dpp_sum64(zsd*zsd), a2 = dpp_sum64(rsd*zsd);
  float b0 = dpp_sum64(zn0*zn0), b1 = dpp_sum64(zn0*rsd);
  float b2 = dpp_sum64(zn1*zn1), b3 = dpp_sum64(zn1*rsd);
  if (lane == 63) {
    red[22 + 0*8 + wv] = a0; red[22 + 1*8 + wv] = a1; red[22 + 2*8 + wv] = a2;
    red[22 + 3*8 + wv] = b0; red[22 + 4*8 + wv] = b1;
    red[22 + 5*8 + wv] = b2; red[22 + 6*8 + wv] = b3;
  }
  __syncthreads();                                   // B8'

  if (tid < 64) {
    const int qi = tid >> 3, k = tid & 7;
    float v = (qi < 7) ? red[22 + 8*qi + k] : 0.f;
    v += __shfl_xor(v, 1); v += __shfl_xor(v, 2); v += __shfl_xor(v, 4);
    const float s0 = __shfl(v, 0),  s1 = __shfl(v, 8),  s2 = __shfl(v, 16);
    const float t0 = __shfl(v, 24), t1 = __shfl(v, 32);
    const float t2 = __shfl(v, 40), t3 = __shfl(v, 48);
    if (tid == 0) {
      const float nr = fmaxf(sqrtf(s0), EPS_);
      const float nz = fmaxf(sqrtf(s1), EPS_);
      const float c1 = s2 / (nr * nz);
      const float c2a = t1 / (fmaxf(sqrtf(t0), EPS_) * nr);
      const float c2b = t3 / (fmaxf(sqrtf(t2), EPS_) * nr);
      abae[2*r]     = fmaxf(c2a - c1 + 1.0f, 0.0f);
      abae[2*r + 1] = fmaxf(c2b - c1 + 1.0f, 0.0f);
    }
  }
}

// ---------------- K4: merged segment-sum apply + FM + offloaded U/J (blocks B_SZ, B_SZ+1) ----------------
__global__ __launch_bounds__(512) void k_aggfm(
    const int* __restrict__ cnt, const int* __restrict__ scol,
    const float* __restrict__ sval, const float* __restrict__ rs,
    const float* __restrict__ fcw, const float* __restrict__ V,
    const float* __restrict__ Wt, const float* __restrict__ abae,
    float* __restrict__ uae, float* __restrict__ iae,
    float* __restrict__ linb, float* __restrict__ quadb,
    float* __restrict__ uj)
{
  __shared__ __align__(16) float ivec[2*D_DIM];
  __shared__ float redw[8];
  __shared__ float qpart[10];
  __shared__ float cninvS[A_DIM];
  const int b = blockIdx.x;
  const int tid = threadIdx.x, lane = tid & 63, wv = tid >> 6;

  if (b == B_SZ) {               // U_loss: Wt Gram (hidden under the 1024 agg blocks)
    if (tid < 400) {
      const int a = tid / 20, c = tid % 20;
      float dot = 0.f;
      #pragma unroll 4
      for (int d = 0; d < D_DIM; ++d) dot += Wt[d*A_DIM + a] * Wt[d*A_DIM + c];
      ivec[tid] = dot;
    }
    __syncthreads();
    if (tid < A_DIM) cninvS[tid] = 1.0f / fmaxf(sqrtf(ivec[tid*21]), EPS_);
    __syncthreads();
    float u = 0.f;
    if (tid < 400) {
      const int a = tid / 20, c = tid % 20;
      const float g = ivec[tid]*cninvS[a]*cninvS[c] - (a==c ? 1.0f : 0.0f);
      u = g*g;
    }
    #pragma unroll
    for (int o = 32; o > 0; o >>= 1) u += __shfl_xor(u, o);
    if (lane == 0) redw[wv] = u;
    __syncthreads();
    if (tid == 0) {
      float s = 0.f;
      #pragma unroll
      for (int i = 0; i < 8; ++i) s += redw[i];
      uj[0] = s;
    }
    return;
  }
  if (b == B_SZ + 1) {           // J: sum of abae
    float s = 0.f;
    for (int i = tid; i < RN_TOT; i += 512) s += abae[i];
    #pragma unroll
    for (int o = 32; o > 0; o >>= 1) s += __shfl_xor(s, o);
    if (lane == 0) redw[wv] = s;
    __syncthreads();
    if (tid == 0) {
      float t = 0.f;
      #pragma unroll
      for (int i = 0; i < 8; ++i) t += redw[i];
      uj[1] = t;
    }
    return;
  }

  if (tid < D_DIM) {
    int n = cnt[b]; n = n < SLOT_CAP ? n : SLOT_CAP;
    const int* cols = scol + (size_t)b*SLOT_CAP;
    const float* vals = sval + (size_t)b*SLOT_CAP;
    float acc = 0.f;
    for (int j = 0; j < n; ++j) acc += vals[j] * rs[(size_t)cols[j]*D_DIM + tid];
    ivec[tid] = acc;
    uae[(size_t)b*D_DIM + tid] = acc;
  } else if (tid >= 256 && tid < 256 + D_DIM) {
    const int t = tid - 256;
    int n = cnt[B_SZ + b]; n = n < SLOT_CAP ? n : SLOT_CAP;
    const int* cols = scol + (size_t)(B_SZ + b)*SLOT_CAP;
    const float* vals = sval + (size_t)(B_SZ + b)*SLOT_CAP;
    float acc = 0.f;
    for (int j = 0; j < n; ++j) acc += vals[j] * rs[(size_t)cols[j]*D_DIM + t];
    ivec[D_DIM + t] = acc;
    iae[(size_t)b*D_DIM + t] = acc;
  }
  __syncthreads();

  float lv = 0.f;
  if (tid < 2*D_DIM) lv = ivec[tid] * fcw[tid];
  #pragma unroll
  for (int o = 32; o > 0; o >>= 1) lv += __shfl_xor(lv, o);
  if (lane == 0) redw[wv] = lv;

  {
    const int k = wv;
    float s1 = 0.f, s2 = 0.f;
    for (int f = lane; f < 2*D_DIM; f += 64) {
      const float x = ivec[f];
      const float vk = V[f*10 + k];
      s1 += x*vk; s2 += x*x*vk*vk;
    }
    #pragma unroll
    for (int o = 32; o > 0; o >>= 1) { s1 += __shfl_xor(s1,o); s2 += __shfl_xor(s2,o); }
    if (lane == 0) qpart[k] = s1*s1 - s2;
  }
  if (wv < 2) {
    const int k = 8 + wv;
    float s1 = 0.f, s2 = 0.f;
    for (int f = lane; f < 2*D_DIM; f += 64) {
      const float x = ivec[f];
      const float vk = V[f*10 + k];
      s1 += x*vk; s2 += x*x*vk*vk;
    }
    #pragma unroll
    for (int o = 32; o > 0; o >>= 1) { s1 += __shfl_xor(s1,o); s2 += __shfl_xor(s2,o); }
    if (lane == 0) qpart[k] = s1*s1 - s2;
  }
  __syncthreads();
  if (tid == 0) {
    float lin = 0.f;
    #pragma unroll
    for (int i = 0; i < 8; ++i) lin += redw[i];
    float q = 0.f;
    #pragma unroll
    for (int i = 0; i < 10; ++i) q += qpart[i];
    linb[b] = lin; quadb[b] = q;
  }
}

// ---------------- K5: quad-reduce + prediction + final combine (U/J precomputed) ----------------
__global__ __launch_bounds__(1024) void k_final2(
    const float* __restrict__ quadb, const float* __restrict__ linb,
    const float* __restrict__ fcb, const int* __restrict__ user,
    const int* __restrict__ item, const float* __restrict__ busers,
    const float* __restrict__ bitems, const float* __restrict__ label,
    const float* __restrict__ uj,
    float* __restrict__ pred, float* __restrict__ rl, float* __restrict__ obj)
{
  __shared__ float sA[16], sC[16];
  __shared__ float quad_s;
  const int tid = threadIdx.x;
  const int lane = tid & 63;
  const int wv = tid >> 6;

  float q = quadb[tid];
  #pragma unroll
  for (int o = 32; o > 0; o >>= 1) q += __shfl_xor(q, o);
  if (lane == 0) sA[wv] = q;
  __syncthreads();
  if (wv == 0) {
    float s = (lane < 16) ? sA[lane] : 0.f;
    #pragma unroll
    for (int o = 32; o > 0; o >>= 1) s += __shfl_xor(s, o);
    if (lane == 0) quad_s = s;
  }
  __syncthreads();

  const float p = 0.5f*quad_s + linb[tid] + fcb[0]
                + busers[user[tid]] + bitems[item[tid]];
  pred[tid] = p;
  const float dd = p - label[tid];
  const float myrl = dd*dd;
  rl[tid] = myrl;

  float ms = myrl;
  #pragma unroll
  for (int o = 32; o > 0; o >>= 1) ms += __shfl_xor(ms, o);
  if (lane == 0) sC[wv] = ms;
  __syncthreads();
  if (tid == 0) {
    float Ms = 0.f;
    for (int i = 0; i < 16; ++i) Ms += sC[i];
    obj[0] = Ms/1024.0f + 0.01f*(uj[1]/8192.0f) + 0.01f*(uj[0]/400.0f);
  }
}

extern "C" void kernel_launch(void* const* d_in, const int* in_sizes, int n_in,
                              void* d_out, int out_size, void* d_ws, size_t ws_size,
                              hipStream_t stream) {
  const int*   hist   = (const int*)  d_in[0];
  const int*   neg    = (const int*)  d_in[1];
  const int*   user   = (const int*)  d_in[2];
  const int*   item   = (const int*)  d_in[3];
  const float* label  = (const float*)d_in[4];
  const int*   uidx   = (const int*)  d_in[5];
  const float* uval   = (const float*)d_in[6];
  const int*   iidx   = (const int*)  d_in[7];
  const float* ival   = (const float*)d_in[8];
  const float* emb    = (const float*)d_in[9];
  const float* Wm     = (const float*)d_in[10];
  const float* Ww     = (const float*)d_in[11];
  const float* bw     = (const float*)d_in[12];
  const float* Wt     = (const float*)d_in[13];
  const float* fcw    = (const float*)d_in[14];
  const float* fcb    = (const float*)d_in[15];
  const float* V      = (const float*)d_in[16];
  const float* busers = (const float*)d_in[17];
  const float* bitems = (const float*)d_in[18];

  float* out  = (float*)d_out;
  float* obj  = out;                       // 1
  float* rl   = out + 1;                   // 1024
  float* abae = out + 1 + B_SZ;            // 8192
  float* pred = out + 1 + B_SZ + RN_TOT;   // 1024
  float* uae  = pred + B_SZ;               // 204800
  float* iae  = uae + (size_t)B_SZ*D_DIM;  // 204800

  float* ws     = (float*)d_ws;
  float* rs     = ws;                              // R*D
  float* ys_all = rs + (size_t)R_TOT*D_DIM;        // R*D
  float* zn_all = ys_all + (size_t)R_TOT*D_DIM;    // RN*D
  float* vv_reg = zn_all + (size_t)RN_TOT*D_DIM;   // R*D region: vvh (fp16) + uj
  float* linb   = vv_reg + (size_t)R_TOT*D_DIM;    // B
  float* quadb  = linb + B_SZ;                     // B
  float* sval   = quadb + B_SZ;                    // 2*B*SLOT_CAP floats
  int*   scol   = (int*)(sval + (size_t)2*B_SZ*SLOT_CAP);   // 2*B*SLOT_CAP ints
  int*   cnt    = scol + (size_t)2*B_SZ*SLOT_CAP;           // 2*B ints
  ushort* emb_h = (ushort*)(cnt + 2*B_SZ);                  // VOCAB*D halves
  ushort* vvh   = (ushort*)vv_reg;                 // R*D halves (first half of region)
  float*  uj    = vv_reg + (size_t)R_TOT*D_DIM/2 + 16;      // past vvh, aligned slack

  const int cast_blocks = (VOCAB_C*D_DIM/4 + 255)/256;      // 6250

  k_cast       <<<cast_blocks, 256, 0, stream>>>(emb, emb_h, cnt);
  k_means_phase<<<S_TOT + NBUCK_BLK, 256, 0, stream>>>(hist, neg, emb_h,
                                                       ys_all, zn_all,
                                                       uidx, uval, iidx, ival,
                                                       cnt, scol, sval, 0, 0);
  k_means_phase<<<S_TOT, 256, 0, stream>>>(hist, neg, emb_h,
                                           ys_all, zn_all,
                                           uidx, uval, iidx, ival,
                                           cnt, scol, sval, VHALF, 1);
  k_matvec     <<<R_TOT/KB_RT, 256, 0, stream>>>(ys_all, Wm, vvh);
  k_attn       <<<R_TOT, 512, 0, stream>>>(hist, emb_h, vvh, Ww, bw, Wt,
                                           zn_all, rs, abae);
  k_aggfm      <<<B_SZ + 2, 512, 0, stream>>>(cnt, scol, sval, rs, fcw, V, Wt, abae,
                                              uae, iae, linb, quadb, uj);
  k_final2     <<<1, 1024, 0, stream>>>(quadb, linb, fcb, user, item, busers, bitems,
                                        label, uj, pred, rl, obj);
}

// Round 13
// 273.354 us; speedup vs baseline: 1.1320x; 1.1320x over previous
//
#include <hip/hip_runtime.h>
#include <hip/hip_fp16.h>
#include <math.h>

// Problem constants (match reference)
#define R_TOT 4096
#define L_LEN 128
#define D_DIM 200
#define A_DIM 20
#define NEGK  2
#define B_SZ  1024
#define NNZ_C 20480
#define RN_TOT (R_TOT*NEGK)
#define S_TOT (R_TOT + RN_TOT)
#define VOCAB_C 32000
#define VHALF 16000
#define EPS_ 1e-12f
#define SLOT_CAP 64          // Poisson(20) max bin ~45; 64 is safe
#define NBUCK_BLK 160        // 160*256 = 40960 = 2*NNZ_C

__device__ __forceinline__ float4 unpack4(const uint2 u) {
  union { unsigned v; __half2 h; } c0, c1;
  c0.v = u.x; c1.v = u.y;
  const float2 f0 = __half22float2(c0.h);
  const float2 f1 = __half22float2(c1.h);
  return make_float4(f0.x, f0.y, f1.x, f1.y);
}

// ---- packed fp16 dot: v_dot2_f32_f16 (exact f32 products, f32 accumulate) ----
typedef _Float16 h2v __attribute__((ext_vector_type(2)));
__device__ __forceinline__ float fdot2u(unsigned a, unsigned b, float c) {
  union { unsigned u; h2v h; } ua, ub;
  ua.u = a; ub.u = b;
  return __builtin_amdgcn_fdot2(ua.h, ub.h, c, false);
}
__device__ __forceinline__ float dot8f(const uint4 q, const uint4 w, float c) {
  float s = c;
  s = fdot2u(q.x, w.x, s); s = fdot2u(q.y, w.y, s);
  s = fdot2u(q.z, w.z, s); s = fdot2u(q.w, w.w, s);
  return s;
}

// ---- DPP wave reductions (VALU pipe, zero DS-pipe traffic) ----
// rocPRIM sequence: row_shr:1/2/4/8 -> lane 15 of each row; row_bcast15 (0xa) ->
// lane 31 = lanes 0-31; row_bcast31 (0xc) -> lane 63 = full wave.
#define DPPI(old_, src_, ctrl, rmask) \
  __builtin_amdgcn_update_dpp(old_, src_, ctrl, rmask, 0xf, false)

__device__ __forceinline__ float dpp_sum32(float s) {   // lanes 31 & 63 hold half-wave sums
  s += __int_as_float(DPPI(0, __float_as_int(s), 0x111, 0xf));   // row_shr:1
  s += __int_as_float(DPPI(0, __float_as_int(s), 0x112, 0xf));   // row_shr:2
  s += __int_as_float(DPPI(0, __float_as_int(s), 0x114, 0xf));   // row_shr:4
  s += __int_as_float(DPPI(0, __float_as_int(s), 0x118, 0xf));   // row_shr:8
  s += __int_as_float(DPPI(0, __float_as_int(s), 0x142, 0xa));   // row_bcast15
  return s;
}
__device__ __forceinline__ float dpp_sum64(float s) {   // lane 63 holds wave sum
  s = dpp_sum32(s);
  s += __int_as_float(DPPI(0, __float_as_int(s), 0x143, 0xc));   // row_bcast31
  return s;
}
__device__ __forceinline__ float dpp_max64(float s) {   // lane 63 holds wave max
  s = fmaxf(s, __int_as_float(DPPI(__float_as_int(s), __float_as_int(s), 0x111, 0xf)));
  s = fmaxf(s, __int_as_float(DPPI(__float_as_int(s), __float_as_int(s), 0x112, 0xf)));
  s = fmaxf(s, __int_as_float(DPPI(__float_as_int(s), __float_as_int(s), 0x114, 0xf)));
  s = fmaxf(s, __int_as_float(DPPI(__float_as_int(s), __float_as_int(s), 0x118, 0xf)));
  s = fmaxf(s, __int_as_float(DPPI(__float_as_int(s), __float_as_int(s), 0x142, 0xa)));
  s = fmaxf(s, __int_as_float(DPPI(__float_as_int(s), __float_as_int(s), 0x143, 0xc)));
  return s;
}

// ---------------- K0: cast emb -> fp16 table; block 0 also zeroes bucket counters ----------------
__global__ __launch_bounds__(256) void k_cast(
    const float* __restrict__ emb, ushort* __restrict__ emb_h, int* __restrict__ cnt)
{
  if (blockIdx.x == 0) {
    for (int i = threadIdx.x; i < 2*B_SZ; i += 256) cnt[i] = 0;
  }
  const int idx = blockIdx.x*256 + threadIdx.x;
  if (idx < (VOCAB_C*D_DIM)/4) {
    const float4 v = reinterpret_cast<const float4*>(emb)[idx];
    ushort4 o;
    o.x = __half_as_ushort(__float2half(v.x));
    o.y = __half_as_ushort(__float2half(v.y));
    o.z = __half_as_ushort(__float2half(v.z));
    o.w = __half_as_ushort(__float2half(v.w));
    reinterpret_cast<ushort4*>(emb_h)[idx] = o;
  }
}

// ---------------- K1: means, vocab-range phased (2 launches) + bucket tail ----------------
// (R8-verified: per-pass working set 6.4 MB -> L2-resident; out-of-range rows load
// row 0 (L1-hot, ~free) and contribute via x0 FMA — keeps the 16-deep load MLP,
// which R12's compaction experiment proved is the real lever, not VALU count.)
#define ACC8M(Q, M) { \
  const float4 e0_ = unpack4(make_uint2((Q).x,(Q).y)); \
  const float4 e1_ = unpack4(make_uint2((Q).z,(Q).w)); \
  sA.x = fmaf(M, e0_.x, sA.x); sA.y = fmaf(M, e0_.y, sA.y); \
  sA.z = fmaf(M, e0_.z, sA.z); sA.w = fmaf(M, e0_.w, sA.w); \
  sB.x = fmaf(M, e1_.x, sB.x); sB.y = fmaf(M, e1_.y, sB.y); \
  sB.z = fmaf(M, e1_.z, sB.z); sB.w = fmaf(M, e1_.w, sB.w); }

__global__ __launch_bounds__(256, 8) void k_means_phase(
    const int* __restrict__ hist, const int* __restrict__ neg,
    const ushort* __restrict__ emb_h,
    float* __restrict__ ys_all, float* __restrict__ zn_all,
    const int* __restrict__ uidx, const float* __restrict__ uval,
    const int* __restrict__ iidx, const float* __restrict__ ival,
    int* __restrict__ cnt, int* __restrict__ scol, float* __restrict__ sval,
    int lo, int finalize)
{
  const int sb = blockIdx.x;
  const int tid = threadIdx.x;

  if (sb >= S_TOT) {            // bucket tail — phase A only (phase B grid = S_TOT)
    const int g = (sb - S_TOT)*256 + tid;
    if (g < NNZ_C) {
      const int b = uidx[g];
      const int slot = atomicAdd(&cnt[b], 1);
      if (slot < SLOT_CAP) {
        scol[b*SLOT_CAP + slot] = uidx[NNZ_C + g];
        sval[b*SLOT_CAP + slot] = uval[g];
      }
    } else {
      const int g2 = g - NNZ_C;
      const int b = iidx[g2];
      const int slot = atomicAdd(&cnt[B_SZ + b], 1);
      if (slot < SLOT_CAP) {
        scol[(B_SZ + b)*SLOT_CAP + slot] = iidx[NNZ_C + g2];
        sval[(B_SZ + b)*SLOT_CAP + slot] = ival[g2];
      }
    }
    return;
  }

  __shared__ int widx[L_LEN];
  __shared__ __align__(16) float part[8][D_DIM];
  const bool is_pos = (sb < R_TOT);
  const int* src = is_pos ? (hist + (size_t)sb*L_LEN)
                          : (neg + (size_t)(sb - R_TOT)*L_LEN);
  if (tid < L_LEN) widx[tid] = src[tid];
  __syncthreads();

  const int c5 = tid & 31;       // column chunk (active if < 25)
  const int j  = tid >> 5;       // 0..7 row group
  float4 sA = {0.f,0.f,0.f,0.f}, sB = {0.f,0.f,0.f,0.f};
  if (c5 < 25) {
    const size_t coff = 8*c5;
    #pragma unroll
    for (int half = 0; half < 2; ++half) {
      const int base = j + 64*half;
      int   wv_[8]; float m_[8];
      #pragma unroll
      for (int k = 0; k < 8; ++k) {
        const int w = widx[base + 8*k];
        const bool in = ((unsigned)(w - lo) < (unsigned)VHALF);
        wv_[k] = in ? w : 0;
        m_[k]  = in ? 1.f : 0.f;
      }
      const uint4 q0 = *reinterpret_cast<const uint4*>(emb_h + (size_t)wv_[0]*D_DIM + coff);
      const uint4 q1 = *reinterpret_cast<const uint4*>(emb_h + (size_t)wv_[1]*D_DIM + coff);
      const uint4 q2 = *reinterpret_cast<const uint4*>(emb_h + (size_t)wv_[2]*D_DIM + coff);
      const uint4 q3 = *reinterpret_cast<const uint4*>(emb_h + (size_t)wv_[3]*D_DIM + coff);
      const uint4 q4 = *reinterpret_cast<const uint4*>(emb_h + (size_t)wv_[4]*D_DIM + coff);
      const uint4 q5 = *reinterpret_cast<const uint4*>(emb_h + (size_t)wv_[5]*D_DIM + coff);
      const uint4 q6 = *reinterpret_cast<const uint4*>(emb_h + (size_t)wv_[6]*D_DIM + coff);
      const uint4 q7 = *reinterpret_cast<const uint4*>(emb_h + (size_t)wv_[7]*D_DIM + coff);
      ACC8M(q0, m_[0]) ACC8M(q1, m_[1]) ACC8M(q2, m_[2]) ACC8M(q3, m_[3])
      ACC8M(q4, m_[4]) ACC8M(q5, m_[5]) ACC8M(q6, m_[6]) ACC8M(q7, m_[7])
    }
    *reinterpret_cast<float4*>(&part[j][8*c5])     = sA;
    *reinterpret_cast<float4*>(&part[j][8*c5 + 4]) = sB;
  }
  __syncthreads();
  float* dst = is_pos ? (ys_all + (size_t)sb*D_DIM)
                      : (zn_all + (size_t)(sb - R_TOT)*D_DIM);
  if (tid < D_DIM) {
    float a = 0.f;
    #pragma unroll
    for (int j2 = 0; j2 < 8; ++j2) a += part[j2][tid];
    if (finalize) dst[tid] = (dst[tid] + a) * (1.0f/128.0f);
    else          dst[tid] = a;
  }
}

// ---------------- K2: V = Y @ Wm (16 reviews/block) — fp16 output for fdot2 ----------------
#define KB_RT 16
__global__ __launch_bounds__(256, 2) void k_matvec(
    const float* __restrict__ ys_all, const float* __restrict__ Wm,
    ushort* __restrict__ vvh)
{
  __shared__ float ysl[KB_RT][D_DIM];
  const int r0 = blockIdx.x * KB_RT;
  const int tid = threadIdx.x;
  for (int i = tid; i < KB_RT*D_DIM; i += 256)
    ysl[i / D_DIM][i % D_DIM] = ys_all[(size_t)r0*D_DIM + i];
  __syncthreads();
  if (tid < D_DIM) {
    float acc[KB_RT];
    #pragma unroll
    for (int r = 0; r < KB_RT; ++r) acc[r] = 0.f;
    #pragma unroll 4
    for (int k = 0; k < D_DIM; ++k) {
      const float w = Wm[k*D_DIM + tid];
      #pragma unroll
      for (int r = 0; r < KB_RT; ++r) acc[r] += ysl[r][k] * w;
    }
    #pragma unroll
    for (int r = 0; r < KB_RT; ++r)
      vvh[(size_t)(r0 + r)*D_DIM + tid] = __half_as_ushort(__float2half(acc[r]));
  }
}

// ---------------- K3: attn — register tile + DPP + fdot2; (512,8), 8 barriers, padded part ----------------
// Best-known config (R9/R10, 276-277 µs total): register-resident tile (R7, broke the
// 82 µs DS-pipe floor), fdot2 packed dots (R9, 65->60), padded part[17] (conflicts->0),
// redundant per-wave softmax max (one barrier saved).
__global__ __launch_bounds__(512, 8) void k_attn(
    const int* __restrict__ hist, const ushort* __restrict__ emb_h,
    const ushort* __restrict__ vvh,
    const float* __restrict__ Ww, const float* __restrict__ bw,
    const float* __restrict__ Wt, const float* __restrict__ zn_all,
    float* __restrict__ rs_out, float* __restrict__ abae)
{
  __shared__ __align__(16) float part[D_DIM][17];    // padded: conflict-free zs-sum
  __shared__ __align__(16) float ax[L_LEN];
  __shared__ __align__(16) ushort axh[L_LEN];
  __shared__ __align__(16) float zs[D_DIM];
  __shared__ __align__(16) float ubuf[240];
  int*   widx  = reinterpret_cast<int*>(ubuf);
  float* ptile = ubuf;
  float* red   = ubuf + 160;

  const int r = blockIdx.x;
  const int tid = threadIdx.x, lane = tid & 63, wv = tid >> 6;
  const int c5 = tid & 31;
  const int j  = tid >> 5;
  const bool act = (c5 < 25);
  const int coff = 8*c5;

  if (tid < L_LEN) widx[tid] = hist[r*L_LEN + tid];
  uint4 v8u = make_uint4(0,0,0,0);
  if (act) v8u = *reinterpret_cast<const uint4*>(vvh + (size_t)r*D_DIM + coff);
  __syncthreads();                                   // B1

  uint4 q0,q1,q2,q3,q4,q5,q6,q7;
  q0=q1=q2=q3=q4=q5=q6=q7=make_uint4(0,0,0,0);
  float zn0 = 0.f, zn1 = 0.f;
  float p0=0.f,p1=0.f,p2=0.f,p3=0.f,p4=0.f,p5=0.f,p6=0.f,p7=0.f;
  if (act) {
    q0 = *reinterpret_cast<const uint4*>(emb_h + (size_t)widx[j +   0]*D_DIM + coff);
    q1 = *reinterpret_cast<const uint4*>(emb_h + (size_t)widx[j +  16]*D_DIM + coff);
    q2 = *reinterpret_cast<const uint4*>(emb_h + (size_t)widx[j +  32]*D_DIM + coff);
    q3 = *reinterpret_cast<const uint4*>(emb_h + (size_t)widx[j +  48]*D_DIM + coff);
    q4 = *reinterpret_cast<const uint4*>(emb_h + (size_t)widx[j +  64]*D_DIM + coff);
    q5 = *reinterpret_cast<const uint4*>(emb_h + (size_t)widx[j +  80]*D_DIM + coff);
    q6 = *reinterpret_cast<const uint4*>(emb_h + (size_t)widx[j +  96]*D_DIM + coff);
    q7 = *reinterpret_cast<const uint4*>(emb_h + (size_t)widx[j + 112]*D_DIM + coff);
  }
  if (tid < D_DIM) {
    zn0 = zn_all[(size_t)(2*r)*D_DIM + tid];
    zn1 = zn_all[(size_t)(2*r + 1)*D_DIM + tid];
  }
  if (act) {
    p0 = dot8f(q0, v8u, 0.f); p1 = dot8f(q1, v8u, 0.f);
    p2 = dot8f(q2, v8u, 0.f); p3 = dot8f(q3, v8u, 0.f);
    p4 = dot8f(q4, v8u, 0.f); p5 = dot8f(q5, v8u, 0.f);
    p6 = dot8f(q6, v8u, 0.f); p7 = dot8f(q7, v8u, 0.f);
  }
  p0 = dpp_sum32(p0); p1 = dpp_sum32(p1); p2 = dpp_sum32(p2); p3 = dpp_sum32(p3);
  p4 = dpp_sum32(p4); p5 = dpp_sum32(p5); p6 = dpp_sum32(p6); p7 = dpp_sum32(p7);
  if (c5 == 31) {
    ax[j]      = p0; ax[j + 16]  = p1; ax[j + 32]  = p2; ax[j + 48]  = p3;
    ax[j + 64] = p4; ax[j + 80]  = p5; ax[j + 96]  = p6; ax[j + 112] = p7;
  }
  __syncthreads();                                   // B2

  float mx = fmaxf(ax[lane], ax[lane + 64]);
  mx = dpp_max64(mx);
  const float M = __int_as_float(__builtin_amdgcn_readlane(__float_as_int(mx), 63));

  if (tid < L_LEN) {
    const float e = expf(ax[tid] - M);
    axh[tid] = __half_as_ushort(__float2half(e));
    const float s = dpp_sum64(e);
    if (lane == 63) red[1 + wv] = s;
  }
  __syncthreads();                                   // B3'

  if (act) {
    const int Y  = 25*j + c5;
    const int l0 = (8*Y) & 127;
    const int v0 = Y >> 4;
    const int sl = Y & 15;
    const uint4 ax8u = *reinterpret_cast<const uint4*>(axh + l0);
    part[v0 +   0][sl] = dot8f(q0, ax8u, 0.f);
    part[v0 +  25][sl] = dot8f(q1, ax8u, 0.f);
    part[v0 +  50][sl] = dot8f(q2, ax8u, 0.f);
    part[v0 +  75][sl] = dot8f(q3, ax8u, 0.f);
    part[v0 + 100][sl] = dot8f(q4, ax8u, 0.f);
    part[v0 + 125][sl] = dot8f(q5, ax8u, 0.f);
    part[v0 + 150][sl] = dot8f(q6, ax8u, 0.f);
    part[v0 + 175][sl] = dot8f(q7, ax8u, 0.f);
  }
  __syncthreads();                                   // B4'

  if (tid < D_DIM) {
    const float Sinv = 1.0f / (red[1] + red[2]);
    float s = 0.f;
    #pragma unroll
    for (int i = 0; i < 16; ++i) s += part[tid][i];
    zs[tid] = s * Sinv;
  }
  __syncthreads();                                   // B5'

  if (tid < 160) {
    const int a = tid % 20, jj = tid / 20;
    float s = 0.f;
    #pragma unroll
    for (int ii = 0; ii < 25; ++ii) {
      const int d = jj + 8*ii;
      s += zs[d] * Ww[a*D_DIM + d];
    }
    ptile[tid] = s;
  }
  __syncthreads();                                   // B6'
  if (tid < A_DIM) {
    float s = bw[tid];
    #pragma unroll
    for (int jj = 0; jj < 8; ++jj) s += ptile[jj*20 + tid];
    red[2 + tid] = s;
  }
  __syncthreads();                                   // B7'

  float rsd = 0.f, zsd = 0.f;
  if (tid < D_DIM) {
    float acc = 0.f;
    #pragma unroll
    for (int a = 0; a < A_DIM; ++a) acc += red[2+a] * Wt[tid*A_DIM + a];
    rsd = acc; zsd = zs[tid];
    rs_out[(size_t)r*D_DIM + tid] = acc;
  } else { zn0 = 0.f; zn1 = 0.f; }
  float a0 = dpp_sum64(rsd*rsd), a1 = dpp_sum64(zsd*zsd), a2 = dpp_sum64(rsd*zsd);
  float b0 = dpp_sum64(zn0*zn0), b1 = dpp_sum64(zn0*rsd);
  float b2 = dpp_sum64(zn1*zn1), b3 = dpp_sum64(zn1*rsd);
  if (lane == 63) {
    red[22 + 0*8 + wv] = a0; red[22 + 1*8 + wv] = a1; red[22 + 2*8 + wv] = a2;
    red[22 + 3*8 + wv] = b0; red[22 + 4*8 + wv] = b1;
    red[22 + 5*8 + wv] = b2; red[22 + 6*8 + wv] = b3;
  }
  __syncthreads();                                   // B8'

  if (tid < 64) {
    const int qi = tid >> 3, k = tid & 7;
    float v = (qi < 7) ? red[22 + 8*qi + k] : 0.f;
    v += __shfl_xor(v, 1); v += __shfl_xor(v, 2); v += __shfl_xor(v, 4);
    const float s0 = __shfl(v, 0),  s1 = __shfl(v, 8),  s2 = __shfl(v, 16);
    const float t0 = __shfl(v, 24), t1 = __shfl(v, 32);
    const float t2 = __shfl(v, 40), t3 = __shfl(v, 48);
    if (tid == 0) {
      const float nr = fmaxf(sqrtf(s0), EPS_);
      const float nz = fmaxf(sqrtf(s1), EPS_);
      const float c1 = s2 / (nr * nz);
      const float c2a = t1 / (fmaxf(sqrtf(t0), EPS_) * nr);
      const float c2b = t3 / (fmaxf(sqrtf(t2), EPS_) * nr);
      abae[2*r]     = fmaxf(c2a - c1 + 1.0f, 0.0f);
      abae[2*r + 1] = fmaxf(c2b - c1 + 1.0f, 0.0f);
    }
  }
}

// ---------------- K4: merged segment-sum apply + FM + offloaded U/J (blocks B_SZ, B_SZ+1) ----------------
__global__ __launch_bounds__(512) void k_aggfm(
    const int* __restrict__ cnt, const int* __restrict__ scol,
    const float* __restrict__ sval, const float* __restrict__ rs,
    const float* __restrict__ fcw, const float* __restrict__ V,
    const float* __restrict__ Wt, const float* __restrict__ abae,
    float* __restrict__ uae, float* __restrict__ iae,
    float* __restrict__ linb, float* __restrict__ quadb,
    float* __restrict__ uj)
{
  __shared__ __align__(16) float ivec[2*D_DIM];
  __shared__ float redw[8];
  __shared__ float qpart[10];
  __shared__ float cninvS[A_DIM];
  const int b = blockIdx.x;
  const int tid = threadIdx.x, lane = tid & 63, wv = tid >> 6;

  if (b == B_SZ) {               // U_loss: Wt Gram (hidden under the 1024 agg blocks)
    if (tid < 400) {
      const int a = tid / 20, c = tid % 20;
      float dot = 0.f;
      #pragma unroll 4
      for (int d = 0; d < D_DIM; ++d) dot += Wt[d*A_DIM + a] * Wt[d*A_DIM + c];
      ivec[tid] = dot;
    }
    __syncthreads();
    if (tid < A_DIM) cninvS[tid] = 1.0f / fmaxf(sqrtf(ivec[tid*21]), EPS_);
    __syncthreads();
    float u = 0.f;
    if (tid < 400) {
      const int a = tid / 20, c = tid % 20;
      const float g = ivec[tid]*cninvS[a]*cninvS[c] - (a==c ? 1.0f : 0.0f);
      u = g*g;
    }
    #pragma unroll
    for (int o = 32; o > 0; o >>= 1) u += __shfl_xor(u, o);
    if (lane == 0) redw[wv] = u;
    __syncthreads();
    if (tid == 0) {
      float s = 0.f;
      #pragma unroll
      for (int i = 0; i < 8; ++i) s += redw[i];
      uj[0] = s;
    }
    return;
  }
  if (b == B_SZ + 1) {           // J: sum of abae
    float s = 0.f;
    for (int i = tid; i < RN_TOT; i += 512) s += abae[i];
    #pragma unroll
    for (int o = 32; o > 0; o >>= 1) s += __shfl_xor(s, o);
    if (lane == 0) redw[wv] = s;
    __syncthreads();
    if (tid == 0) {
      float t = 0.f;
      #pragma unroll
      for (int i = 0; i < 8; ++i) t += redw[i];
      uj[1] = t;
    }
    return;
  }

  if (tid < D_DIM) {
    int n = cnt[b]; n = n < SLOT_CAP ? n : SLOT_CAP;
    const int* cols = scol + (size_t)b*SLOT_CAP;
    const float* vals = sval + (size_t)b*SLOT_CAP;
    float acc = 0.f;
    for (int j = 0; j < n; ++j) acc += vals[j] * rs[(size_t)cols[j]*D_DIM + tid];
    ivec[tid] = acc;
    uae[(size_t)b*D_DIM + tid] = acc;
  } else if (tid >= 256 && tid < 256 + D_DIM) {
    const int t = tid - 256;
    int n = cnt[B_SZ + b]; n = n < SLOT_CAP ? n : SLOT_CAP;
    const int* cols = scol + (size_t)(B_SZ + b)*SLOT_CAP;
    const float* vals = sval + (size_t)(B_SZ + b)*SLOT_CAP;
    float acc = 0.f;
    for (int j = 0; j < n; ++j) acc += vals[j] * rs[(size_t)cols[j]*D_DIM + t];
    ivec[D_DIM + t] = acc;
    iae[(size_t)b*D_DIM + t] = acc;
  }
  __syncthreads();

  float lv = 0.f;
  if (tid < 2*D_DIM) lv = ivec[tid] * fcw[tid];
  #pragma unroll
  for (int o = 32; o > 0; o >>= 1) lv += __shfl_xor(lv, o);
  if (lane == 0) redw[wv] = lv;

  {
    const int k = wv;
    float s1 = 0.f, s2 = 0.f;
    for (int f = lane; f < 2*D_DIM; f += 64) {
      const float x = ivec[f];
      const float vk = V[f*10 + k];
      s1 += x*vk; s2 += x*x*vk*vk;
    }
    #pragma unroll
    for (int o = 32; o > 0; o >>= 1) { s1 += __shfl_xor(s1,o); s2 += __shfl_xor(s2,o); }
    if (lane == 0) qpart[k] = s1*s1 - s2;
  }
  if (wv < 2) {
    const int k = 8 + wv;
    float s1 = 0.f, s2 = 0.f;
    for (int f = lane; f < 2*D_DIM; f += 64) {
      const float x = ivec[f];
      const float vk = V[f*10 + k];
      s1 += x*vk; s2 += x*x*vk*vk;
    }
    #pragma unroll
    for (int o = 32; o > 0; o >>= 1) { s1 += __shfl_xor(s1,o); s2 += __shfl_xor(s2,o); }
    if (lane == 0) qpart[k] = s1*s1 - s2;
  }
  __syncthreads();
  if (tid == 0) {
    float lin = 0.f;
    #pragma unroll
    for (int i = 0; i < 8; ++i) lin += redw[i];
    float q = 0.f;
    #pragma unroll
    for (int i = 0; i < 10; ++i) q += qpart[i];
    linb[b] = lin; quadb[b] = q;
  }
}

// ---------------- K5: quad-reduce + prediction + final combine (U/J precomputed) ----------------
__global__ __launch_bounds__(1024) void k_final2(
    const float* __restrict__ quadb, const float* __restrict__ linb,
    const float* __restrict__ fcb, const int* __restrict__ user,
    const int* __restrict__ item, const float* __restrict__ busers,
    const float* __restrict__ bitems, const float* __restrict__ label,
    const float* __restrict__ uj,
    float* __restrict__ pred, float* __restrict__ rl, float* __restrict__ obj)
{
  __shared__ float sA[16], sC[16];
  __shared__ float quad_s;
  const int tid = threadIdx.x;
  const int lane = tid & 63;
  const int wv = tid >> 6;

  float q = quadb[tid];
  #pragma unroll
  for (int o = 32; o > 0; o >>= 1) q += __shfl_xor(q, o);
  if (lane == 0) sA[wv] = q;
  __syncthreads();
  if (wv == 0) {
    float s = (lane < 16) ? sA[lane] : 0.f;
    #pragma unroll
    for (int o = 32; o > 0; o >>= 1) s += __shfl_xor(s, o);
    if (lane == 0) quad_s = s;
  }
  __syncthreads();

  const float p = 0.5f*quad_s + linb[tid] + fcb[0]
                + busers[user[tid]] + bitems[item[tid]];
  pred[tid] = p;
  const float dd = p - label[tid];
  const float myrl = dd*dd;
  rl[tid] = myrl;

  float ms = myrl;
  #pragma unroll
  for (int o = 32; o > 0; o >>= 1) ms += __shfl_xor(ms, o);
  if (lane == 0) sC[wv] = ms;
  __syncthreads();
  if (tid == 0) {
    float Ms = 0.f;
    for (int i = 0; i < 16; ++i) Ms += sC[i];
    obj[0] = Ms/1024.0f + 0.01f*(uj[1]/8192.0f) + 0.01f*(uj[0]/400.0f);
  }
}

extern "C" void kernel_launch(void* const* d_in, const int* in_sizes, int n_in,
                              void* d_out, int out_size, void* d_ws, size_t ws_size,
                              hipStream_t stream) {
  const int*   hist   = (const int*)  d_in[0];
  const int*   neg    = (const int*)  d_in[1];
  const int*   user   = (const int*)  d_in[2];
  const int*   item   = (const int*)  d_in[3];
  const float* label  = (const float*)d_in[4];
  const int*   uidx   = (const int*)  d_in[5];
  const float* uval   = (const float*)d_in[6];
  const int*   iidx   = (const int*)  d_in[7];
  const float* ival   = (const float*)d_in[8];
  const float* emb    = (const float*)d_in[9];
  const float* Wm     = (const float*)d_in[10];
  const float* Ww     = (const float*)d_in[11];
  const float* bw     = (const float*)d_in[12];
  const float* Wt     = (const float*)d_in[13];
  const float* fcw    = (const float*)d_in[14];
  const float* fcb    = (const float*)d_in[15];
  const float* V      = (const float*)d_in[16];
  const float* busers = (const float*)d_in[17];
  const float* bitems = (const float*)d_in[18];

  float* out  = (float*)d_out;
  float* obj  = out;                       // 1
  float* rl   = out + 1;                   // 1024
  float* abae = out + 1 + B_SZ;            // 8192
  float* pred = out + 1 + B_SZ + RN_TOT;   // 1024
  float* uae  = pred + B_SZ;               // 204800
  float* iae  = uae + (size_t)B_SZ*D_DIM;  // 204800

  float* ws     = (float*)d_ws;
  float* rs     = ws;                              // R*D
  float* ys_all = rs + (size_t)R_TOT*D_DIM;        // R*D
  float* zn_all = ys_all + (size_t)R_TOT*D_DIM;    // RN*D
  float* vv_reg = zn_all + (size_t)RN_TOT*D_DIM;   // R*D region: vvh (fp16) + uj
  float* linb   = vv_reg + (size_t)R_TOT*D_DIM;    // B
  float* quadb  = linb + B_SZ;                     // B
  float* sval   = quadb + B_SZ;                    // 2*B*SLOT_CAP floats
  int*   scol   = (int*)(sval + (size_t)2*B_SZ*SLOT_CAP);   // 2*B*SLOT_CAP ints
  int*   cnt    = scol + (size_t)2*B_SZ*SLOT_CAP;           // 2*B ints
  ushort* emb_h = (ushort*)(cnt + 2*B_SZ);                  // VOCAB*D halves
  ushort* vvh   = (ushort*)vv_reg;                 // R*D halves (first half of region)
  float*  uj    = vv_reg + (size_t)R_TOT*D_DIM/2 + 16;      // past vvh, aligned slack

  const int cast_blocks = (VOCAB_C*D_DIM/4 + 255)/256;      // 6250

  k_cast       <<<cast_blocks, 256, 0, stream>>>(emb, emb_h, cnt);
  k_means_phase<<<S_TOT + NBUCK_BLK, 256, 0, stream>>>(hist, neg, emb_h,
                                                       ys_all, zn_all,
                                                       uidx, uval, iidx, ival,
                                                       cnt, scol, sval, 0, 0);
  k_means_phase<<<S_TOT, 256, 0, stream>>>(hist, neg, emb_h,
                                           ys_all, zn_all,
                                           uidx, uval, iidx, ival,
                                           cnt, scol, sval, VHALF, 1);
  k_matvec     <<<R_TOT/KB_RT, 256, 0, stream>>>(ys_all, Wm, vvh);
  k_attn       <<<R_TOT, 512, 0, stream>>>(hist, emb_h, vvh, Ww, bw, Wt,
                                           zn_all, rs, abae);
  k_aggfm      <<<B_SZ + 2, 512, 0, stream>>>(cnt, scol, sval, rs, fcw, V, Wt, abae,
                                              uae, iae, linb, quadb, uj);
  k_final2     <<<1, 1024, 0, stream>>>(quadb, linb, fcb, user, item, busers, bitems,
                                        label, uj, pred, rl, obj);
}